// Round 1
// baseline (791.404 us; speedup 1.0000x reference)
//
#include <hip/hip_runtime.h>
#include <math.h>

// ---------------- problem constants ----------------
#define NPX   4096      // 64*64
#define NSC   36864     // 9*4096 scores
#define NKPRE 2000
#define NKPOST 256

// ---------------- ws layout (float offsets) ----------------
// feats (12845056 f) aliases h (1048576 f): h dead before k_align writes feats.
#define F_FEATS 0
#define F_H     0
#define F_FMT   12845056
#define F_PART  13893632
#define F_UKEY  15613952
#define F_BX    15650816
#define F_BY    15687680
#define F_BW    15724544
#define F_BH    15761408
#define F_HIST  15798272
#define F_CAND  15863808
#define F_MASK  15872000
#define F_RBX   16000000
#define F_RBY   16002000
#define F_RBW   16004000
#define F_RBH   16006000
#define F_SEL   16008000
#define F_RXS   16008256
#define F_RYS   16008512
#define F_RWS   16008768
#define F_RHS   16009024
#define F_META  16009280
// total = 16009296 floats = 64,037,184 bytes (~61.1 MB)

typedef unsigned long long u64;
typedef unsigned int u32;

// ---------------- init: zero hist + meta ----------------
__global__ void k_init(int* __restrict__ hist, int* __restrict__ meta) {
    int i = blockIdx.x * 256 + threadIdx.x;
    if (i < 65536) hist[i] = 0;
    if (i < 16) meta[i] = 0;
}

// ---------------- transpose x (C,H,W) -> fmt (H*W, C) ----------------
__global__ void __launch_bounds__(256) k_transpose(const float* __restrict__ x,
                                                   float* __restrict__ fmt) {
    __shared__ float t[64][65];
    int pt = blockIdx.x;          // 64 px tiles
    int ct = blockIdx.y;          // 4 c tiles
    int tid = threadIdx.x;
    int px0 = pt * 64, c0 = ct * 64;
    int ln = tid & 63, sub = tid >> 6;
    for (int p = 0; p < 16; ++p) {
        int cl = p * 4 + sub;
        t[ln][cl] = x[(c0 + cl) * 4096 + px0 + ln];
    }
    __syncthreads();
    for (int p = 0; p < 16; ++p) {
        int pl = p * 4 + sub;
        fmt[(px0 + pl) * 256 + c0 + ln] = t[pl][ln];
    }
}

// ---------------- conv3x3 SAME, 256->256, + bias -> h ----------------
// block: 4 out-channels x 512 px (each thread 2 px), grid (8 px-chunks, 64 o-quads)
__global__ void __launch_bounds__(256) k_conv(const float* __restrict__ xin,
                                              const float* __restrict__ rpn_w,
                                              const float* __restrict__ rpn_b,
                                              float* __restrict__ h) {
    __shared__ float lw[9216];    // [c][9][o4]
    int tid = threadIdx.x;
    int o0 = blockIdx.y * 4;
    for (int e = tid; e < 9216; e += 256) {
        int o = e / 2304, r = e % 2304;
        lw[r * 4 + o] = rpn_w[(o0 + o) * 2304 + r];
    }
    __syncthreads();
    int px0 = blockIdx.x * 512 + tid;
    int px1 = px0 + 256;
    int y0 = px0 >> 6, xc = px0 & 63, y1 = px1 >> 6;
    float a0[4] = {0.f, 0.f, 0.f, 0.f};
    float a1[4] = {0.f, 0.f, 0.f, 0.f};
    for (int c = 0; c < 256; ++c) {
        const float* xb = xin + c * 4096;
        #pragma unroll
        for (int ky = 0; ky < 3; ++ky) {
            int yy0 = y0 + ky - 1; bool vy0 = ((unsigned)yy0 < 64u);
            int yy1 = y1 + ky - 1; bool vy1 = ((unsigned)yy1 < 64u);
            #pragma unroll
            for (int kx = 0; kx < 3; ++kx) {
                int xx = xc + kx - 1; bool vx = ((unsigned)xx < 64u);
                float xv0 = (vy0 && vx) ? xb[yy0 * 64 + xx] : 0.f;
                float xv1 = (vy1 && vx) ? xb[yy1 * 64 + xx] : 0.f;
                float4 w = *(const float4*)&lw[(c * 9 + ky * 3 + kx) * 4];
                a0[0] += xv0 * w.x; a0[1] += xv0 * w.y; a0[2] += xv0 * w.z; a0[3] += xv0 * w.w;
                a1[0] += xv1 * w.x; a1[1] += xv1 * w.y; a1[2] += xv1 * w.z; a1[3] += xv1 * w.w;
            }
        }
    }
    #pragma unroll
    for (int j = 0; j < 4; ++j) {
        float b = rpn_b[o0 + j];
        h[(o0 + j) * 4096 + px0] = a0[j] + b;
        h[(o0 + j) * 4096 + px1] = a1[j] + b;
    }
}

// ---------------- rpn heads + decode + histogram ----------------
// 16 blocks x 256 threads, 1 px/thread, 54 accumulators
__global__ void __launch_bounds__(256) k_heads(const float* __restrict__ h,
        const float* __restrict__ cls_w, const float* __restrict__ cls_b,
        const float* __restrict__ tfm_w, const float* __restrict__ tfm_b,
        const float* __restrict__ anchors,
        float* __restrict__ out_cls, float* __restrict__ out_tfm,
        u32* __restrict__ ukey, float* __restrict__ bxp, float* __restrict__ byp,
        float* __restrict__ bwp, float* __restrict__ bhp, int* __restrict__ hist) {
    __shared__ float w[256 * 56];
    int tid = threadIdx.x;
    for (int e = tid; e < 54 * 256; e += 256) {
        int o = e >> 8, c = e & 255;
        float v = (o < 18) ? cls_w[o * 256 + c] : tfm_w[(o - 18) * 256 + c];
        w[c * 56 + o] = v;
    }
    __syncthreads();
    int px = blockIdx.x * 256 + tid;
    float acc[54];
    #pragma unroll
    for (int o = 0; o < 54; ++o) acc[o] = 0.f;
    for (int c = 0; c < 256; ++c) {
        float hv = h[c * 4096 + px];
        #pragma unroll
        for (int o = 0; o < 54; ++o) acc[o] += hv * w[c * 56 + o];
    }
    #pragma unroll
    for (int o = 0; o < 18; ++o) out_cls[o * 4096 + px] = acc[o] + cls_b[o];
    #pragma unroll
    for (int o = 0; o < 36; ++o) out_tfm[o * 4096 + px] = acc[18 + o] + tfm_b[o];
    float jx = (float)(px & 63), iy = (float)(px >> 6);
    #pragma unroll
    for (int a = 0; a < 9; ++a) {
        float pos = acc[2 * a] + cls_b[2 * a];
        float neg = acc[2 * a + 1] + cls_b[2 * a + 1];
        float d = pos - neg;
        float sc = 1.f / (1.f + expf(-d));
        float t0 = acc[18 + a * 4 + 0] + tfm_b[a * 4 + 0];
        float t1 = acc[18 + a * 4 + 1] + tfm_b[a * 4 + 1];
        float t2 = acc[18 + a * 4 + 2] + tfm_b[a * 4 + 2];
        float t3 = acc[18 + a * 4 + 3] + tfm_b[a * 4 + 3];
        float ah = anchors[a * 2 + 0], aw = anchors[a * 2 + 1];
        float bx = jx + aw * (t1 - 0.5f) / 16.f;
        float by = iy + ah * (t0 - 0.5f) / 16.f;
        float bw = aw / 16.f * expf(t3);
        float bh = ah / 16.f * expf(t2);
        bx = fminf(fmaxf(bx, 0.f), 63.f);
        by = fminf(fmaxf(by, 0.f), 63.f);
        bw = fminf(fmaxf(bx + bw, 0.f), 63.f) - bx;
        bh = fminf(fmaxf(by + bh, 0.f), 63.f) - by;
        int idx = a * 4096 + px;
        u32 bits = __float_as_uint(sc);
        u32 u = (bits & 0x80000000u) ? ~bits : (bits ^ 0x80000000u);
        ukey[idx] = u;
        bxp[idx] = bx; byp[idx] = by; bwp[idx] = bw; bhp[idx] = bh;
        atomicAdd(&hist[u >> 16], 1);
    }
}

// ---------------- find cutoff bin for top-2000 ----------------
__global__ void __launch_bounds__(1024) k_scan(const int* __restrict__ hist,
                                               int* __restrict__ meta) {
    __shared__ int s[1024];
    int t = threadIdx.x;
    int base = 65536 - 64 * (t + 1);
    int sum = 0;
    for (int i = 0; i < 64; ++i) sum += hist[base + i];
    s[t] = sum;
    __syncthreads();
    int own = sum;
    for (int off = 1; off < 1024; off <<= 1) {
        int v = (t >= off) ? s[t - off] : 0;
        __syncthreads();
        s[t] += v;
        __syncthreads();
    }
    int cum = s[t], prev = cum - own;
    if (prev < NKPRE && cum >= NKPRE) {
        int c = prev;
        int b = 65535 - 64 * t;
        for (int i = 0; i < 64; ++i) {
            c += hist[b - i];
            if (c >= NKPRE) { meta[0] = b - i; break; }
        }
    }
}

// ---------------- compact candidates (bin >= cutoff) ----------------
__global__ void k_compact(const u32* __restrict__ ukey, const int* __restrict__ meta,
                          u64* __restrict__ cand, int* __restrict__ cnt) {
    int i = blockIdx.x * 256 + threadIdx.x;
    if (i >= NSC) return;
    u32 u = ukey[i];
    if ((int)(u >> 16) >= meta[0]) {
        int pos = atomicAdd(cnt, 1);
        if (pos < 4096) cand[pos] = (((u64)(~u)) << 32) | (u32)i;
    }
}

// ---------------- bitonic sort 4096 -> top 2000 boxes ----------------
__global__ void __launch_bounds__(1024) k_sort(const u64* __restrict__ cand,
        const int* __restrict__ meta,
        const float* __restrict__ bxp, const float* __restrict__ byp,
        const float* __restrict__ bwp, const float* __restrict__ bhp,
        float* __restrict__ rbx, float* __restrict__ rby,
        float* __restrict__ rbw, float* __restrict__ rbh) {
    __shared__ u64 s[4096];
    int t = threadIdx.x;
    int cnt = meta[1]; if (cnt > 4096) cnt = 4096;
    for (int i = t; i < 4096; i += 1024)
        s[i] = (i < cnt) ? cand[i] : 0xFFFFFFFFFFFFFFFFULL;
    for (int k = 2; k <= 4096; k <<= 1)
        for (int j = k >> 1; j > 0; j >>= 1) {
            __syncthreads();
            for (int i = t; i < 4096; i += 1024) {
                int ixj = i ^ j;
                if (ixj > i) {
                    u64 a = s[i], b = s[ixj];
                    bool up = ((i & k) == 0);
                    if ((a > b) == up) { s[i] = b; s[ixj] = a; }
                }
            }
        }
    __syncthreads();
    for (int r = t; r < NKPRE; r += 1024) {
        int idx = (int)(u32)(s[r] & 0xFFFFFFFFULL);
        rbx[r] = bxp[idx]; rby[r] = byp[idx]; rbw[r] = bwp[idx]; rbh[r] = bhp[idx];
    }
}

// ---------------- IoU suppression bitmask ----------------
__global__ void __launch_bounds__(256) k_mask(const float* __restrict__ rbx,
        const float* __restrict__ rby, const float* __restrict__ rbw,
        const float* __restrict__ rbh, u64* __restrict__ mask) {
    int i = blockIdx.x;
    int lane = threadIdx.x & 63;
    int wave = threadIdx.x >> 6;
    float bxi = rbx[i], byi = rby[i], bwi = rbw[i], bhi = rbh[i];
    float x2i = bxi + bwi, y2i = byi + bhi, ari = bwi * bhi;
    for (int w = wave; w < 32; w += 4) {
        int j = w * 64 + lane;
        bool p = false;
        if (j < NKPRE && j > i) {
            float bxj = rbx[j], byj = rby[j], bwj = rbw[j], bhj = rbh[j];
            float x2j = bxj + bwj, y2j = byj + bhj, arj = bwj * bhj;
            float ix = fmaxf(bxi, bxj), iy = fmaxf(byi, byj);
            float iw = fmaxf(fminf(x2i, x2j) - ix, 0.f);
            float ih = fmaxf(fminf(y2i, y2j) - iy, 0.f);
            float inter = iw * ih;
            float iou = inter / (ari + arj - inter);
            p = iou > 0.7f;
        }
        u64 b = __ballot(p);
        if (lane == 0) mask[i * 32 + w] = b;
    }
}

// ---------------- greedy NMS scan (1 wave) + select 256 ----------------
__global__ void __launch_bounds__(64) k_nms(const u64* __restrict__ mask,
        const float* __restrict__ rbx, const float* __restrict__ rby,
        const float* __restrict__ rbw, const float* __restrict__ rbh,
        int* __restrict__ sel, float* __restrict__ rxs, float* __restrict__ rys,
        float* __restrict__ rws, float* __restrict__ rhs) {
    __shared__ int klist[256];
    int lane = threadIdx.x;
    int lw = lane & 31;
    u64 removed = 0ULL;
    int kcount = 0;
    u64 pf[8];
    #pragma unroll
    for (int s = 0; s < 8; ++s) pf[s] = mask[s * 32 + lw];
    bool done = false;
    for (int ib = 0; ib < NKPRE; ib += 8) {
        if (done) break;
        #pragma unroll
        for (int s = 0; s < 8; ++s) {
            int ii = ib + s;
            u64 row = pf[s];
            int nx = ii + 8;
            if (nx < NKPRE) pf[s] = mask[nx * 32 + lw];
            if (!done) {
                int wi = ii >> 6;
                u64 wv = __shfl(removed, wi);
                if (((wv >> (ii & 63)) & 1ULL) == 0ULL) {
                    if (lane == 0) klist[kcount] = ii;
                    kcount++;
                    if (lane < 32) removed |= row;
                    if (kcount == NKPOST) done = true;
                }
            }
        }
    }
    if (kcount < NKPOST) {       // fill with suppressed indices, ascending
        for (int ii = 0; ii < NKPRE; ++ii) {
            int wi = ii >> 6;
            u64 wv = __shfl(removed, wi);
            if ((wv >> (ii & 63)) & 1ULL) {
                if (lane == 0) klist[kcount] = ii;
                kcount++;
                if (kcount == NKPOST) break;
            }
        }
    }
    __syncthreads();
    for (int s = lane; s < NKPOST; s += 64) {
        int id = klist[s];
        sel[s] = id;
        rxs[s] = rbx[id]; rys[s] = rby[id]; rws[s] = rbw[id]; rhs[s] = rbh[id];
    }
}

// ---------------- ROI align + 2x2 maxpool -> feats[roi][c*196+cell] ----------------
__global__ void __launch_bounds__(256) k_align(const float* __restrict__ fmt,
        const float* __restrict__ rxs, const float* __restrict__ rys,
        const float* __restrict__ rws, const float* __restrict__ rhs,
        float* __restrict__ feats) {
    __shared__ float buf[64 * 197];
    __shared__ int xs0[28], ys0[28];
    __shared__ float wxs[28], wys[28];
    int roi = blockIdx.x;
    int tid = threadIdx.x;
    float rx = rxs[roi], ry = rys[roi], rw = rws[roi], rh = rhs[roi];
    if (tid < 28) {
        float g = rx + ((float)tid + 0.5f) * rw / 28.f;
        g = fminf(fmaxf(g, 0.f), 63.f);
        int x0 = (int)floorf(g); x0 = min(max(x0, 0), 62);
        xs0[tid] = x0; wxs[tid] = g - (float)x0;
        float g2 = ry + ((float)tid + 0.5f) * rh / 28.f;
        g2 = fminf(fmaxf(g2, 0.f), 63.f);
        int y0 = (int)floorf(g2); y0 = min(max(y0, 0), 62);
        ys0[tid] = y0; wys[tid] = g2 - (float)y0;
    }
    __syncthreads();
    int cl = tid & 63, cg = tid >> 6;
    for (int cc = 0; cc < 4; ++cc) {
        int c0 = cc * 64;
        for (int cell = cg; cell < 196; cell += 4) {
            int py = cell / 14, pxc = cell % 14;
            float m = -INFINITY;
            #pragma unroll
            for (int dy = 0; dy < 2; ++dy) {
                int sy = py * 2 + dy;
                int y0 = ys0[sy]; float wy = wys[sy];
                #pragma unroll
                for (int dx = 0; dx < 2; ++dx) {
                    int sx = pxc * 2 + dx;
                    int x0 = xs0[sx]; float wx = wxs[sx];
                    int base = (y0 * 64 + x0) * 256 + c0 + cl;
                    float f00 = fmt[base];
                    float f10 = fmt[base + 256];
                    float f01 = fmt[base + 64 * 256];
                    float f11 = fmt[base + 64 * 256 + 256];
                    float v = f00 * (1.f - wy) * (1.f - wx) + f01 * wy * (1.f - wx)
                            + f10 * (1.f - wy) * wx + f11 * wy * wx;
                    m = fmaxf(m, v);
                }
            }
            buf[cl * 197 + cell] = m;
        }
        __syncthreads();
        for (int e = tid; e < 64 * 196; e += 256) {
            int c = e / 196, cell = e % 196;
            feats[roi * 50176 + (c0 + c) * 196 + cell] = buf[c * 197 + cell];
        }
        __syncthreads();
    }
}

// ---------------- head GEMM partial (K-split 64) ----------------
// grid (64 ksplit, 4 roi-tiles), block 256: thread = 4 roi x 8 o
__global__ void __launch_bounds__(256) k_gemm(const float* __restrict__ feats,
        const float* __restrict__ head_w, float* __restrict__ part) {
    __shared__ float lf[28 * 68];
    __shared__ float lw[28 * 132];
    int ks = blockIdx.x, rt = blockIdx.y;
    int tid = threadIdx.x;
    int rg = tid & 15, og = tid >> 4;
    int roi0 = rt * 64;
    float acc[4][8];
    #pragma unroll
    for (int r = 0; r < 4; ++r)
        #pragma unroll
        for (int j = 0; j < 8; ++j) acc[r][j] = 0.f;
    for (int st = 0; st < 28; ++st) {
        int kb = ks * 784 + st * 28;
        __syncthreads();
        #pragma unroll
        for (int p = 0; p < 7; ++p) {
            int e = p * 256 + tid;
            int k = e % 28, r = e / 28;
            lf[k * 68 + r] = feats[(roi0 + r) * 50176 + kb + k];
        }
        for (int e = tid; e < 28 * 132; e += 256) {
            int k = e % 28, o = e / 28;
            lw[k * 132 + o] = (o < 105) ? head_w[o * 50176 + kb + k] : 0.f;
        }
        __syncthreads();
        #pragma unroll
        for (int kk = 0; kk < 28; ++kk) {
            float4 f = *(const float4*)&lf[kk * 68 + rg * 4];
            float4 wa = *(const float4*)&lw[kk * 132 + og * 8];
            float4 wb = *(const float4*)&lw[kk * 132 + og * 8 + 4];
            float fv[4] = {f.x, f.y, f.z, f.w};
            float wv[8] = {wa.x, wa.y, wa.z, wa.w, wb.x, wb.y, wb.z, wb.w};
            #pragma unroll
            for (int r = 0; r < 4; ++r)
                #pragma unroll
                for (int j = 0; j < 8; ++j) acc[r][j] += fv[r] * wv[j];
        }
    }
    #pragma unroll
    for (int r = 0; r < 4; ++r) {
        int roi = roi0 + rg * 4 + r;
        #pragma unroll
        for (int j = 0; j < 8; ++j) {
            int o = og * 8 + j;
            if (o < 105) part[(ks * 256 + roi) * 105 + o] = acc[r][j];
        }
    }
}

// ---------------- deterministic K-split reduce + bias -> cls/tfm outputs ----------------
__global__ void k_reduce(const float* __restrict__ part, const float* __restrict__ head_b,
                         float* __restrict__ out_cls, float* __restrict__ out_tfm) {
    int e = blockIdx.x * 256 + threadIdx.x;
    if (e >= 26880) return;
    int roi = e / 105, o = e % 105;
    float s = 0.f;
    for (int ks = 0; ks < 64; ++ks) s += part[ks * 26880 + e];
    s += head_b[o];
    if (o < 21) out_cls[roi * 21 + o] = s;
    else        out_tfm[roi * 84 + (o - 21)] = s;
}

// ---------------- argmax + final/proposal bbox ----------------
__global__ void __launch_bounds__(256) k_final(const float* __restrict__ out_cls,
        const float* __restrict__ out_tfm,
        const float* __restrict__ rxs, const float* __restrict__ rys,
        const float* __restrict__ rws, const float* __restrict__ rhs,
        float* __restrict__ prop, float* __restrict__ fbox) {
    int r = threadIdx.x;
    float best = out_cls[r * 21]; int det = 0;
    for (int o = 1; o < 21; ++o) {
        float v = out_cls[r * 21 + o];
        if (v > best) { best = v; det = o; }
    }
    float t0 = out_tfm[r * 84 + det * 4 + 0];
    float t1 = out_tfm[r * 84 + det * 4 + 1];
    float t2 = out_tfm[r * 84 + det * 4 + 2];
    float t3 = out_tfm[r * 84 + det * 4 + 3];
    float X = rxs[r] * 16.f, Y = rys[r] * 16.f, Wd = rws[r] * 16.f, Hd = rhs[r] * 16.f;
    float fx = X + Wd * t1, fy = Y + Hd * t0;
    float fw = Wd * expf(t3), fh = Hd * expf(t2);
    prop[r * 5 + 0] = 0.f; prop[r * 5 + 1] = X;  prop[r * 5 + 2] = Y;
    prop[r * 5 + 3] = Wd;  prop[r * 5 + 4] = Hd;
    fbox[r * 5 + 0] = 0.f; fbox[r * 5 + 1] = fx; fbox[r * 5 + 2] = fy;
    fbox[r * 5 + 3] = fw;  fbox[r * 5 + 4] = fh;
}

extern "C" void kernel_launch(void* const* d_in, const int* in_sizes, int n_in,
                              void* d_out, int out_size, void* d_ws, size_t ws_size,
                              hipStream_t stream) {
    const float* x      = (const float*)d_in[0];
    const float* rpn_w  = (const float*)d_in[1];
    const float* rpn_b  = (const float*)d_in[2];
    const float* cls_w  = (const float*)d_in[3];
    const float* cls_b  = (const float*)d_in[4];
    const float* tfm_w  = (const float*)d_in[5];
    const float* tfm_b  = (const float*)d_in[6];
    const float* head_w = (const float*)d_in[7];
    const float* head_b = (const float*)d_in[8];
    const float* anch   = (const float*)d_in[9];
    float* out = (float*)d_out;
    float* ws  = (float*)d_ws;

    float* h     = ws + F_H;
    float* fmt   = ws + F_FMT;
    float* feats = ws + F_FEATS;
    float* part  = ws + F_PART;
    u32*   ukey  = (u32*)(ws + F_UKEY);
    float* bxp   = ws + F_BX;
    float* byp   = ws + F_BY;
    float* bwp   = ws + F_BW;
    float* bhp   = ws + F_BH;
    int*   hist  = (int*)(ws + F_HIST);
    u64*   cand  = (u64*)(ws + F_CAND);
    u64*   mask  = (u64*)(ws + F_MASK);
    float* rbx   = ws + F_RBX;
    float* rby   = ws + F_RBY;
    float* rbw   = ws + F_RBW;
    float* rbh   = ws + F_RBH;
    int*   sel   = (int*)(ws + F_SEL);
    float* rxs   = ws + F_RXS;
    float* rys   = ws + F_RYS;
    float* rws_p = ws + F_RWS;
    float* rhs_p = ws + F_RHS;
    int*   meta  = (int*)(ws + F_META);

    float* out_rpncls = out + 0;
    float* out_rpntfm = out + 73728;
    float* out_prop   = out + 221184;
    float* out_fbox   = out + 222464;
    float* out_fcls   = out + 223744;
    float* out_ftfm   = out + 229120;

    k_init<<<256, 256, 0, stream>>>(hist, meta);
    k_transpose<<<dim3(64, 4), 256, 0, stream>>>(x, fmt);
    k_conv<<<dim3(8, 64), 256, 0, stream>>>(x, rpn_w, rpn_b, h);
    k_heads<<<16, 256, 0, stream>>>(h, cls_w, cls_b, tfm_w, tfm_b, anch,
                                    out_rpncls, out_rpntfm, ukey, bxp, byp, bwp, bhp, hist);
    k_scan<<<1, 1024, 0, stream>>>(hist, meta);
    k_compact<<<144, 256, 0, stream>>>(ukey, meta, cand, meta + 1);
    k_sort<<<1, 1024, 0, stream>>>(cand, meta, bxp, byp, bwp, bhp, rbx, rby, rbw, rbh);
    k_mask<<<2000, 256, 0, stream>>>(rbx, rby, rbw, rbh, mask);
    k_nms<<<1, 64, 0, stream>>>(mask, rbx, rby, rbw, rbh, sel, rxs, rys, rws_p, rhs_p);
    k_align<<<256, 256, 0, stream>>>(fmt, rxs, rys, rws_p, rhs_p, feats);
    k_gemm<<<dim3(64, 4), 256, 0, stream>>>(feats, head_w, part);
    k_reduce<<<105, 256, 0, stream>>>(part, head_b, out_fcls, out_ftfm);
    k_final<<<1, 256, 0, stream>>>(out_fcls, out_ftfm, rxs, rys, rws_p, rhs_p,
                                   out_prop, out_fbox);
}

// Round 2
// 670.766 us; speedup vs baseline: 1.1799x; 1.1799x over previous
//
#include <hip/hip_runtime.h>
#include <math.h>

// ---------------- problem constants ----------------
#define NPX   4096      // 64*64
#define NSC   36864     // 9*4096 scores
#define NKPRE 2000
#define NKPOST 256
#define GKS   98        // head-gemm K splits (K chunk 512)

// ---------------- ws layout (float offsets) ----------------
// aliases: h (1.05M) under feats (12.85M): h dead before k_align writes feats.
//          fmt (1.05M) under part (2.63M): fmt dead before k_gemm writes part.
#define F_FEATS 0
#define F_H     0
#define F_PART  12845056
#define F_FMT   12845056
#define F_UKEY  15479296
#define F_BX    15516160
#define F_BY    15553024
#define F_BW    15589888
#define F_BH    15626752
#define F_HIST  15663616
#define F_CAND  15729152
#define F_MASK  15737344
#define F_RBX   15865344
#define F_RBY   15867344
#define F_RBW   15869344
#define F_RBH   15871344
#define F_SEL   15873344
#define F_RXS   15873600
#define F_RYS   15873856
#define F_RWS   15874112
#define F_RHS   15874368
#define F_META  15874624
// total = 15,874,640 floats = 63,498,560 bytes (< round-1's proven 64.04 MB)

typedef unsigned long long u64;
typedef unsigned int u32;

// ---------------- init: zero hist + meta ----------------
__global__ void k_init(int* __restrict__ hist, int* __restrict__ meta) {
    int i = blockIdx.x * 256 + threadIdx.x;
    if (i < 65536) hist[i] = 0;
    if (i < 16) meta[i] = 0;
}

// ---------------- transpose x (C,H,W) -> fmt (H*W, C) ----------------
__global__ void __launch_bounds__(256) k_transpose(const float* __restrict__ x,
                                                   float* __restrict__ fmt) {
    __shared__ float t[64][65];
    int pt = blockIdx.x;          // 64 px tiles
    int ct = blockIdx.y;          // 4 c tiles
    int tid = threadIdx.x;
    int px0 = pt * 64, c0 = ct * 64;
    int ln = tid & 63, sub = tid >> 6;
    for (int p = 0; p < 16; ++p) {
        int cl = p * 4 + sub;
        t[ln][cl] = x[(c0 + cl) * 4096 + px0 + ln];
    }
    __syncthreads();
    for (int p = 0; p < 16; ++p) {
        int pl = p * 4 + sub;
        fmt[(px0 + pl) * 256 + c0 + ln] = t[pl][ln];
    }
}

// ---------------- conv3x3 SAME, 256->256, + bias -> h ----------------
__global__ void __launch_bounds__(256) k_conv(const float* __restrict__ xin,
                                              const float* __restrict__ rpn_w,
                                              const float* __restrict__ rpn_b,
                                              float* __restrict__ h) {
    __shared__ float lw[9216];    // [c][9][o4]
    int tid = threadIdx.x;
    int o0 = blockIdx.y * 4;
    for (int e = tid; e < 9216; e += 256) {
        int o = e / 2304, r = e % 2304;
        lw[r * 4 + o] = rpn_w[(o0 + o) * 2304 + r];
    }
    __syncthreads();
    int px0 = blockIdx.x * 512 + tid;
    int px1 = px0 + 256;
    int y0 = px0 >> 6, xc = px0 & 63, y1 = px1 >> 6;
    float a0[4] = {0.f, 0.f, 0.f, 0.f};
    float a1[4] = {0.f, 0.f, 0.f, 0.f};
    for (int c = 0; c < 256; ++c) {
        const float* xb = xin + c * 4096;
        #pragma unroll
        for (int ky = 0; ky < 3; ++ky) {
            int yy0 = y0 + ky - 1; bool vy0 = ((unsigned)yy0 < 64u);
            int yy1 = y1 + ky - 1; bool vy1 = ((unsigned)yy1 < 64u);
            #pragma unroll
            for (int kx = 0; kx < 3; ++kx) {
                int xx = xc + kx - 1; bool vx = ((unsigned)xx < 64u);
                float xv0 = (vy0 && vx) ? xb[yy0 * 64 + xx] : 0.f;
                float xv1 = (vy1 && vx) ? xb[yy1 * 64 + xx] : 0.f;
                float4 w = *(const float4*)&lw[(c * 9 + ky * 3 + kx) * 4];
                a0[0] += xv0 * w.x; a0[1] += xv0 * w.y; a0[2] += xv0 * w.z; a0[3] += xv0 * w.w;
                a1[0] += xv1 * w.x; a1[1] += xv1 * w.y; a1[2] += xv1 * w.z; a1[3] += xv1 * w.w;
            }
        }
    }
    #pragma unroll
    for (int j = 0; j < 4; ++j) {
        float b = rpn_b[o0 + j];
        h[(o0 + j) * 4096 + px0] = a0[j] + b;
        h[(o0 + j) * 4096 + px1] = a1[j] + b;
    }
}

// ---------------- rpn heads + decode + histogram (v2: 128 blocks) ----------------
// block: 32 px, threads = (og 0..7) x (px 0..31); og covers 7 of 56 (54 real) outs
__global__ void __launch_bounds__(256) k_heads(const float* __restrict__ h,
        const float* __restrict__ cls_w, const float* __restrict__ cls_b,
        const float* __restrict__ tfm_w, const float* __restrict__ tfm_b,
        const float* __restrict__ anchors,
        float* __restrict__ out_cls, float* __restrict__ out_tfm,
        u32* __restrict__ ukey, float* __restrict__ bxp, float* __restrict__ byp,
        float* __restrict__ bwp, float* __restrict__ bhp, int* __restrict__ hist) {
    __shared__ float w[256 * 56];   // 57,344 B
    __shared__ float ds[32 * 55];   //  7,040 B  (decode scratch: [px][o])
    int tid = threadIdx.x;
    int px0 = blockIdx.x * 32;
    for (int e = tid; e < 54 * 256; e += 256) {
        int o = e >> 8, c = e & 255;
        float v = (o < 18) ? cls_w[o * 256 + c] : tfm_w[(o - 18) * 256 + c];
        w[c * 56 + o] = v;
    }
    __syncthreads();
    int ploc = tid & 31, og = tid >> 5;     // og 0..7
    int px = px0 + ploc;
    float acc[7];
    #pragma unroll
    for (int j = 0; j < 7; ++j) acc[j] = 0.f;
    for (int c = 0; c < 256; ++c) {
        float hv = h[c * 4096 + px];
        #pragma unroll
        for (int j = 0; j < 7; ++j) acc[j] += hv * w[c * 56 + og * 7 + j];
    }
    #pragma unroll
    for (int j = 0; j < 7; ++j) {
        int o = og * 7 + j;
        if (o < 54) {
            float b = (o < 18) ? cls_b[o] : tfm_b[o - 18];
            float val = acc[j] + b;
            if (o < 18) out_cls[o * 4096 + px] = val;
            else        out_tfm[(o - 18) * 4096 + px] = val;
            ds[ploc * 55 + o] = val;
        }
    }
    __syncthreads();
    for (int t = tid; t < 288; t += 256) {
        int a = t >> 5, p = t & 31;
        int pxx = px0 + p;
        float pos = ds[p * 55 + 2 * a];
        float neg = ds[p * 55 + 2 * a + 1];
        float d = pos - neg;
        float sc = 1.f / (1.f + expf(-d));
        float t0 = ds[p * 55 + 18 + 4 * a + 0];
        float t1 = ds[p * 55 + 18 + 4 * a + 1];
        float t2 = ds[p * 55 + 18 + 4 * a + 2];
        float t3 = ds[p * 55 + 18 + 4 * a + 3];
        float ah = anchors[a * 2 + 0], aw = anchors[a * 2 + 1];
        float jx = (float)(pxx & 63), iy = (float)(pxx >> 6);
        float bx = jx + aw * (t1 - 0.5f) / 16.f;
        float by = iy + ah * (t0 - 0.5f) / 16.f;
        float bw = aw / 16.f * expf(t3);
        float bh = ah / 16.f * expf(t2);
        bx = fminf(fmaxf(bx, 0.f), 63.f);
        by = fminf(fmaxf(by, 0.f), 63.f);
        bw = fminf(fmaxf(bx + bw, 0.f), 63.f) - bx;
        bh = fminf(fmaxf(by + bh, 0.f), 63.f) - by;
        int idx = a * 4096 + pxx;
        u32 bits = __float_as_uint(sc);
        u32 u = (bits & 0x80000000u) ? ~bits : (bits ^ 0x80000000u);
        ukey[idx] = u;
        bxp[idx] = bx; byp[idx] = by; bwp[idx] = bw; bhp[idx] = bh;
        atomicAdd(&hist[u >> 16], 1);
    }
}

// ---------------- find cutoff bin for top-2000 ----------------
__global__ void __launch_bounds__(1024) k_scan(const int* __restrict__ hist,
                                               int* __restrict__ meta) {
    __shared__ int s[1024];
    int t = threadIdx.x;
    int base = 65536 - 64 * (t + 1);
    int sum = 0;
    for (int i = 0; i < 64; ++i) sum += hist[base + i];
    s[t] = sum;
    __syncthreads();
    int own = sum;
    for (int off = 1; off < 1024; off <<= 1) {
        int v = (t >= off) ? s[t - off] : 0;
        __syncthreads();
        s[t] += v;
        __syncthreads();
    }
    int cum = s[t], prev = cum - own;
    if (prev < NKPRE && cum >= NKPRE) {
        int c = prev;
        int b = 65535 - 64 * t;
        for (int i = 0; i < 64; ++i) {
            c += hist[b - i];
            if (c >= NKPRE) { meta[0] = b - i; break; }
        }
    }
}

// ---------------- compact candidates (bin >= cutoff) ----------------
__global__ void k_compact(const u32* __restrict__ ukey, const int* __restrict__ meta,
                          u64* __restrict__ cand, int* __restrict__ cnt) {
    int i = blockIdx.x * 256 + threadIdx.x;
    if (i >= NSC) return;
    u32 u = ukey[i];
    if ((int)(u >> 16) >= meta[0]) {
        int pos = atomicAdd(cnt, 1);
        if (pos < 4096) cand[pos] = (((u64)(~u)) << 32) | (u32)i;
    }
}

// ---------------- bitonic sort 4096 -> top 2000 boxes ----------------
__global__ void __launch_bounds__(1024) k_sort(const u64* __restrict__ cand,
        const int* __restrict__ meta,
        const float* __restrict__ bxp, const float* __restrict__ byp,
        const float* __restrict__ bwp, const float* __restrict__ bhp,
        float* __restrict__ rbx, float* __restrict__ rby,
        float* __restrict__ rbw, float* __restrict__ rbh) {
    __shared__ u64 s[4096];
    int t = threadIdx.x;
    int cnt = meta[1]; if (cnt > 4096) cnt = 4096;
    for (int i = t; i < 4096; i += 1024)
        s[i] = (i < cnt) ? cand[i] : 0xFFFFFFFFFFFFFFFFULL;
    for (int k = 2; k <= 4096; k <<= 1)
        for (int j = k >> 1; j > 0; j >>= 1) {
            __syncthreads();
            for (int i = t; i < 4096; i += 1024) {
                int ixj = i ^ j;
                if (ixj > i) {
                    u64 a = s[i], b = s[ixj];
                    bool up = ((i & k) == 0);
                    if ((a > b) == up) { s[i] = b; s[ixj] = a; }
                }
            }
        }
    __syncthreads();
    for (int r = t; r < NKPRE; r += 1024) {
        int idx = (int)(u32)(s[r] & 0xFFFFFFFFULL);
        rbx[r] = bxp[idx]; rby[r] = byp[idx]; rbw[r] = bwp[idx]; rbh[r] = bhp[idx];
    }
}

// ---------------- IoU suppression bitmask ----------------
__global__ void __launch_bounds__(256) k_mask(const float* __restrict__ rbx,
        const float* __restrict__ rby, const float* __restrict__ rbw,
        const float* __restrict__ rbh, u64* __restrict__ mask) {
    int i = blockIdx.x;
    int lane = threadIdx.x & 63;
    int wave = threadIdx.x >> 6;
    float bxi = rbx[i], byi = rby[i], bwi = rbw[i], bhi = rbh[i];
    float x2i = bxi + bwi, y2i = byi + bhi, ari = bwi * bhi;
    for (int w = wave; w < 32; w += 4) {
        int j = w * 64 + lane;
        bool p = false;
        if (j < NKPRE && j > i) {
            float bxj = rbx[j], byj = rby[j], bwj = rbw[j], bhj = rbh[j];
            float x2j = bxj + bwj, y2j = byj + bhj, arj = bwj * bhj;
            float ix = fmaxf(bxi, bxj), iy = fmaxf(byi, byj);
            float iw = fmaxf(fminf(x2i, x2j) - ix, 0.f);
            float ih = fmaxf(fminf(y2i, y2j) - iy, 0.f);
            float inter = iw * ih;
            float iou = inter / (ari + arj - inter);
            p = iou > 0.7f;
        }
        u64 b = __ballot(p);
        if (lane == 0) mask[i * 32 + w] = b;
    }
}

// ---------------- greedy NMS scan (1 wave) + select 256 ----------------
__global__ void __launch_bounds__(64) k_nms(const u64* __restrict__ mask,
        const float* __restrict__ rbx, const float* __restrict__ rby,
        const float* __restrict__ rbw, const float* __restrict__ rbh,
        int* __restrict__ sel, float* __restrict__ rxs, float* __restrict__ rys,
        float* __restrict__ rws, float* __restrict__ rhs) {
    __shared__ int klist[256];
    int lane = threadIdx.x;
    int lw = lane & 31;
    u64 removed = 0ULL;
    int kcount = 0;
    u64 pf[8];
    #pragma unroll
    for (int s = 0; s < 8; ++s) pf[s] = mask[s * 32 + lw];
    bool done = false;
    for (int ib = 0; ib < NKPRE; ib += 8) {
        if (done) break;
        #pragma unroll
        for (int s = 0; s < 8; ++s) {
            int ii = ib + s;
            u64 row = pf[s];
            int nx = ii + 8;
            if (nx < NKPRE) pf[s] = mask[nx * 32 + lw];
            if (!done) {
                int wi = ii >> 6;
                u64 wv = __shfl(removed, wi);
                if (((wv >> (ii & 63)) & 1ULL) == 0ULL) {
                    if (lane == 0) klist[kcount] = ii;
                    kcount++;
                    if (lane < 32) removed |= row;
                    if (kcount == NKPOST) done = true;
                }
            }
        }
    }
    if (kcount < NKPOST) {       // fill with suppressed indices, ascending
        for (int ii = 0; ii < NKPRE; ++ii) {
            int wi = ii >> 6;
            u64 wv = __shfl(removed, wi);
            if ((wv >> (ii & 63)) & 1ULL) {
                if (lane == 0) klist[kcount] = ii;
                kcount++;
                if (kcount == NKPOST) break;
            }
        }
    }
    __syncthreads();
    for (int s = lane; s < NKPOST; s += 64) {
        int id = klist[s];
        sel[s] = id;
        rxs[s] = rbx[id]; rys[s] = rby[id]; rws[s] = rbw[id]; rhs[s] = rbh[id];
    }
}

// ---------------- ROI align + 2x2 maxpool -> feats[roi][c*196+cell] ----------------
__global__ void __launch_bounds__(256) k_align(const float* __restrict__ fmt,
        const float* __restrict__ rxs, const float* __restrict__ rys,
        const float* __restrict__ rws, const float* __restrict__ rhs,
        float* __restrict__ feats) {
    __shared__ float buf[64 * 197];
    __shared__ int xs0[28], ys0[28];
    __shared__ float wxs[28], wys[28];
    int roi = blockIdx.x;
    int tid = threadIdx.x;
    float rx = rxs[roi], ry = rys[roi], rw = rws[roi], rh = rhs[roi];
    if (tid < 28) {
        float g = rx + ((float)tid + 0.5f) * rw / 28.f;
        g = fminf(fmaxf(g, 0.f), 63.f);
        int x0 = (int)floorf(g); x0 = min(max(x0, 0), 62);
        xs0[tid] = x0; wxs[tid] = g - (float)x0;
        float g2 = ry + ((float)tid + 0.5f) * rh / 28.f;
        g2 = fminf(fmaxf(g2, 0.f), 63.f);
        int y0 = (int)floorf(g2); y0 = min(max(y0, 0), 62);
        ys0[tid] = y0; wys[tid] = g2 - (float)y0;
    }
    __syncthreads();
    int cl = tid & 63, cg = tid >> 6;
    for (int cc = 0; cc < 4; ++cc) {
        int c0 = cc * 64;
        for (int cell = cg; cell < 196; cell += 4) {
            int py = cell / 14, pxc = cell % 14;
            float m = -INFINITY;
            #pragma unroll
            for (int dy = 0; dy < 2; ++dy) {
                int sy = py * 2 + dy;
                int y0 = ys0[sy]; float wy = wys[sy];
                #pragma unroll
                for (int dx = 0; dx < 2; ++dx) {
                    int sx = pxc * 2 + dx;
                    int x0 = xs0[sx]; float wx = wxs[sx];
                    int base = (y0 * 64 + x0) * 256 + c0 + cl;
                    float f00 = fmt[base];
                    float f10 = fmt[base + 256];
                    float f01 = fmt[base + 64 * 256];
                    float f11 = fmt[base + 64 * 256 + 256];
                    float v = f00 * (1.f - wy) * (1.f - wx) + f01 * wy * (1.f - wx)
                            + f10 * (1.f - wy) * wx + f11 * wy * wx;
                    m = fmaxf(m, v);
                }
            }
            buf[cl * 197 + cell] = m;
        }
        __syncthreads();
        for (int e = tid; e < 64 * 196; e += 256) {
            int c = e / 196, cell = e % 196;
            feats[roi * 50176 + (c0 + c) * 196 + cell] = buf[c * 197 + cell];
        }
        __syncthreads();
    }
}

// ---------------- head GEMM partial (v2: K-split 98, 8x8 thread tile) ----------------
// grid (98, 4), block 128 = (rg 0..7) x (og 0..15); 64 roi x 128 o per block
__global__ void __launch_bounds__(128) k_gemm(const float* __restrict__ feats,
        const float* __restrict__ head_w, float* __restrict__ part) {
    __shared__ float lf[64 * 64];    // [kk][roi]
    __shared__ float lw[64 * 128];   // [kk][o]
    int ks = blockIdx.x, rt = blockIdx.y;
    int tid = threadIdx.x;
    int rg = tid >> 4, og = tid & 15;
    int roi0 = rt * 64;
    int k0 = ks * 512;
    float acc[8][8];
    #pragma unroll
    for (int r = 0; r < 8; ++r)
        #pragma unroll
        for (int j = 0; j < 8; ++j) acc[r][j] = 0.f;
    for (int st = 0; st < 8; ++st) {
        int kb = k0 + st * 64;
        __syncthreads();
        {   // stage feats tile: 64 roi x 64 k
            int r = tid >> 1, half = tid & 1;
            const float* src = feats + (size_t)(roi0 + r) * 50176 + kb + half * 32;
            #pragma unroll
            for (int q = 0; q < 8; ++q) {
                float4 v = *(const float4*)(src + q * 4);
                int kk = half * 32 + q * 4;
                lf[(kk + 0) * 64 + r] = v.x;
                lf[(kk + 1) * 64 + r] = v.y;
                lf[(kk + 2) * 64 + r] = v.z;
                lf[(kk + 3) * 64 + r] = v.w;
            }
        }
        {   // stage weight tile: 128 o (105 valid) x 64 k
            int o = tid;
            if (o < 105) {
                const float* src = head_w + (size_t)o * 50176 + kb;
                #pragma unroll
                for (int q = 0; q < 16; ++q) {
                    float4 v = *(const float4*)(src + q * 4);
                    int kk = q * 4;
                    lw[(kk + 0) * 128 + o] = v.x;
                    lw[(kk + 1) * 128 + o] = v.y;
                    lw[(kk + 2) * 128 + o] = v.z;
                    lw[(kk + 3) * 128 + o] = v.w;
                }
            } else {
                #pragma unroll
                for (int q = 0; q < 64; ++q) lw[q * 128 + o] = 0.f;
            }
        }
        __syncthreads();
        #pragma unroll 8
        for (int kk = 0; kk < 64; ++kk) {
            float4 fa = *(const float4*)&lf[kk * 64 + rg * 8];
            float4 fb = *(const float4*)&lf[kk * 64 + rg * 8 + 4];
            float4 wa = *(const float4*)&lw[kk * 128 + og * 8];
            float4 wb = *(const float4*)&lw[kk * 128 + og * 8 + 4];
            float fv[8] = {fa.x, fa.y, fa.z, fa.w, fb.x, fb.y, fb.z, fb.w};
            float wv[8] = {wa.x, wa.y, wa.z, wa.w, wb.x, wb.y, wb.z, wb.w};
            #pragma unroll
            for (int r = 0; r < 8; ++r)
                #pragma unroll
                for (int j = 0; j < 8; ++j) acc[r][j] += fv[r] * wv[j];
        }
    }
    #pragma unroll
    for (int r = 0; r < 8; ++r) {
        int roi = roi0 + rg * 8 + r;
        #pragma unroll
        for (int j = 0; j < 8; ++j) {
            int o = og * 8 + j;
            if (o < 105) part[(size_t)ks * 26880 + roi * 105 + o] = acc[r][j];
        }
    }
}

// ---------------- deterministic K-split reduce + bias -> cls/tfm outputs ----------------
__global__ void k_reduce(const float* __restrict__ part, const float* __restrict__ head_b,
                         float* __restrict__ out_cls, float* __restrict__ out_tfm) {
    int e = blockIdx.x * 256 + threadIdx.x;
    if (e >= 26880) return;
    int roi = e / 105, o = e % 105;
    float s = 0.f;
    for (int ks = 0; ks < GKS; ++ks) s += part[(size_t)ks * 26880 + e];
    s += head_b[o];
    if (o < 21) out_cls[roi * 21 + o] = s;
    else        out_tfm[roi * 84 + (o - 21)] = s;
}

// ---------------- argmax + final/proposal bbox ----------------
__global__ void __launch_bounds__(256) k_final(const float* __restrict__ out_cls,
        const float* __restrict__ out_tfm,
        const float* __restrict__ rxs, const float* __restrict__ rys,
        const float* __restrict__ rws, const float* __restrict__ rhs,
        float* __restrict__ prop, float* __restrict__ fbox) {
    int r = threadIdx.x;
    float best = out_cls[r * 21]; int det = 0;
    for (int o = 1; o < 21; ++o) {
        float v = out_cls[r * 21 + o];
        if (v > best) { best = v; det = o; }
    }
    float t0 = out_tfm[r * 84 + det * 4 + 0];
    float t1 = out_tfm[r * 84 + det * 4 + 1];
    float t2 = out_tfm[r * 84 + det * 4 + 2];
    float t3 = out_tfm[r * 84 + det * 4 + 3];
    float X = rxs[r] * 16.f, Y = rys[r] * 16.f, Wd = rws[r] * 16.f, Hd = rhs[r] * 16.f;
    float fx = X + Wd * t1, fy = Y + Hd * t0;
    float fw = Wd * expf(t3), fh = Hd * expf(t2);
    prop[r * 5 + 0] = 0.f; prop[r * 5 + 1] = X;  prop[r * 5 + 2] = Y;
    prop[r * 5 + 3] = Wd;  prop[r * 5 + 4] = Hd;
    fbox[r * 5 + 0] = 0.f; fbox[r * 5 + 1] = fx; fbox[r * 5 + 2] = fy;
    fbox[r * 5 + 3] = fw;  fbox[r * 5 + 4] = fh;
}

extern "C" void kernel_launch(void* const* d_in, const int* in_sizes, int n_in,
                              void* d_out, int out_size, void* d_ws, size_t ws_size,
                              hipStream_t stream) {
    const float* x      = (const float*)d_in[0];
    const float* rpn_w  = (const float*)d_in[1];
    const float* rpn_b  = (const float*)d_in[2];
    const float* cls_w  = (const float*)d_in[3];
    const float* cls_b  = (const float*)d_in[4];
    const float* tfm_w  = (const float*)d_in[5];
    const float* tfm_b  = (const float*)d_in[6];
    const float* head_w = (const float*)d_in[7];
    const float* head_b = (const float*)d_in[8];
    const float* anch   = (const float*)d_in[9];
    float* out = (float*)d_out;
    float* ws  = (float*)d_ws;

    float* h     = ws + F_H;
    float* fmt   = ws + F_FMT;
    float* feats = ws + F_FEATS;
    float* part  = ws + F_PART;
    u32*   ukey  = (u32*)(ws + F_UKEY);
    float* bxp   = ws + F_BX;
    float* byp   = ws + F_BY;
    float* bwp   = ws + F_BW;
    float* bhp   = ws + F_BH;
    int*   hist  = (int*)(ws + F_HIST);
    u64*   cand  = (u64*)(ws + F_CAND);
    u64*   mask  = (u64*)(ws + F_MASK);
    float* rbx   = ws + F_RBX;
    float* rby   = ws + F_RBY;
    float* rbw   = ws + F_RBW;
    float* rbh   = ws + F_RBH;
    int*   sel   = (int*)(ws + F_SEL);
    float* rxs   = ws + F_RXS;
    float* rys   = ws + F_RYS;
    float* rws_p = ws + F_RWS;
    float* rhs_p = ws + F_RHS;
    int*   meta  = (int*)(ws + F_META);

    float* out_rpncls = out + 0;
    float* out_rpntfm = out + 73728;
    float* out_prop   = out + 221184;
    float* out_fbox   = out + 222464;
    float* out_fcls   = out + 223744;
    float* out_ftfm   = out + 229120;

    k_init<<<256, 256, 0, stream>>>(hist, meta);
    k_transpose<<<dim3(64, 4), 256, 0, stream>>>(x, fmt);
    k_conv<<<dim3(8, 64), 256, 0, stream>>>(x, rpn_w, rpn_b, h);
    k_heads<<<128, 256, 0, stream>>>(h, cls_w, cls_b, tfm_w, tfm_b, anch,
                                     out_rpncls, out_rpntfm, ukey, bxp, byp, bwp, bhp, hist);
    k_scan<<<1, 1024, 0, stream>>>(hist, meta);
    k_compact<<<144, 256, 0, stream>>>(ukey, meta, cand, meta + 1);
    k_sort<<<1, 1024, 0, stream>>>(cand, meta, bxp, byp, bwp, bhp, rbx, rby, rbw, rbh);
    k_mask<<<2000, 256, 0, stream>>>(rbx, rby, rbw, rbh, mask);
    k_nms<<<1, 64, 0, stream>>>(mask, rbx, rby, rbw, rbh, sel, rxs, rys, rws_p, rhs_p);
    k_align<<<256, 256, 0, stream>>>(fmt, rxs, rys, rws_p, rhs_p, feats);
    k_gemm<<<dim3(98, 4), 128, 0, stream>>>(feats, head_w, part);
    k_reduce<<<105, 256, 0, stream>>>(part, head_b, out_fcls, out_ftfm);
    k_final<<<1, 256, 0, stream>>>(out_fcls, out_ftfm, rxs, rys, rws_p, rhs_p,
                                   out_prop, out_fbox);
}